// Round 1
// baseline (1003.808 us; speedup 1.0000x reference)
//
#include <hip/hip_runtime.h>

// MEGNet edge conv: 3x (Linear -> ReLU -> BN-train), BN1/BN2 folded into W2/W3.
// K1: gather-concat GEMM [E,256]@[256,64] bf16 MFMA, h1 bf16 -> ws, stats1 atomics
// fin1: fold BN1 into W2 (bf16 [n][k]) + b2'
// K2: [E,64]@[64,64], h2 bf16, stats2;  fin2; K3 same -> h3; fin3 -> a3,c3
// K4: out = a3*h3 + c3 (fp32)

typedef unsigned short u16;
typedef unsigned int u32;
using bf16x8 = __bf16 __attribute__((ext_vector_type(8)));
using f32x4  = float __attribute__((ext_vector_type(4)));
using u32x4  = u32 __attribute__((ext_vector_type(4)));

#define BN_EPS 1e-5f

__device__ __forceinline__ u16 f2bf(float f) {
    u32 u = __builtin_bit_cast(u32, f);
    u += 0x7fffu + ((u >> 16) & 1u);   // RNE (inputs are finite)
    return (u16)(u >> 16);
}
__device__ __forceinline__ float bf2f(u16 h) {
    return __builtin_bit_cast(float, (u32)h << 16);
}
__device__ __forceinline__ u32 pk2(float a, float b) {
    return (u32)f2bf(a) | ((u32)f2bf(b) << 16);
}

// ---- prep: W1 -> fragment-order bf16 (lane-linear LDS reads, conflict-free),
//            zero the 384 stats floats (harness poisons ws with 0xAA).
__global__ __launch_bounds__(256) void prep_kernel(const float* __restrict__ W1,
                                                   u16* __restrict__ w1f,
                                                   float* __restrict__ statsz) {
    int t = blockIdx.x * 256 + threadIdx.x;
    if (t < 16384) {
        int j = t & 7, lane = (t >> 3) & 63, ct = (t >> 9) & 3, s = (t >> 11) & 1, c = t >> 12;
        int m = lane & 15, quad = lane >> 4;
        int k = c * 64 + s * 32 + quad * 8 + j;
        int n = ct * 16 + m;
        w1f[t] = f2bf(W1[k * 64 + n]);
    }
    if (t < 384) statsz[t] = 0.0f;
}

// ---- K1: concat GEMM, K=256 over {src,dest,edge,gattr[batch]}
__global__ __launch_bounds__(256) void gemm1_kernel(
    const float* __restrict__ src, const float* __restrict__ dst,
    const float* __restrict__ edg, const float* __restrict__ gat,
    const int* __restrict__ batch, const u16* __restrict__ w1f,
    const float* __restrict__ b1, u16* __restrict__ Y,
    float* __restrict__ stats, int tiles)
{
    __shared__ u16 sW[16384];        // fragment-order W1, 32 KB
    __shared__ u16 sOut[64 * 72];    // output staging (pad 72 = 16B-aligned rows)
    __shared__ float sSum[64], sSq[64];

    const int tid = threadIdx.x;
    {   // stage W (contiguous 16B copies)
        const u32x4* g = (const u32x4*)w1f;
        u32x4* l = (u32x4*)sW;
        #pragma unroll
        for (int i = 0; i < 8; i++) l[tid + i * 256] = g[tid + i * 256];
    }
    if (tid < 64) { sSum[tid] = 0.0f; sSq[tid] = 0.0f; }
    __syncthreads();

    const int wave = tid >> 6, lane = tid & 63;
    const int m = lane & 15, quad = lane >> 4;
    const u32x4* sWv = (const u32x4*)sW;

    float bias[4], ssum[4] = {0,0,0,0}, ssq[4] = {0,0,0,0};
    #pragma unroll
    for (int ct = 0; ct < 4; ct++) bias[ct] = b1[ct * 16 + m];

    for (int t = blockIdx.x; t < tiles; t += gridDim.x) {
        const int gr = t * 64 + wave * 16 + m;
        const float* bases[4] = { src + (size_t)gr * 64, dst + (size_t)gr * 64,
                                  edg + (size_t)gr * 64, gat + (size_t)batch[gr] * 64 };
        f32x4 acc[4] = {{0,0,0,0},{0,0,0,0},{0,0,0,0},{0,0,0,0}};
        #pragma unroll
        for (int c = 0; c < 4; c++) {
            const float* p = bases[c] + quad * 8;
            #pragma unroll
            for (int s = 0; s < 2; s++) {
                float4 f0 = *(const float4*)(p + s * 32);
                float4 f1 = *(const float4*)(p + s * 32 + 4);
                u32x4 av = { pk2(f0.x, f0.y), pk2(f0.z, f0.w),
                             pk2(f1.x, f1.y), pk2(f1.z, f1.w) };
                bf16x8 af = __builtin_bit_cast(bf16x8, av);
                #pragma unroll
                for (int ct = 0; ct < 4; ct++) {
                    bf16x8 bf = __builtin_bit_cast(bf16x8, sWv[((c * 2 + s) * 4 + ct) * 64 + lane]);
                    acc[ct] = __builtin_amdgcn_mfma_f32_16x16x32_bf16(af, bf, acc[ct], 0, 0, 0);
                }
            }
        }
        #pragma unroll
        for (int ct = 0; ct < 4; ct++) {
            #pragma unroll
            for (int r = 0; r < 4; r++) {
                float x = fmaxf(acc[ct][r] + bias[ct], 0.0f);
                ssum[ct] += x;
                ssq[ct] = fmaf(x, x, ssq[ct]);
                sOut[(wave * 16 + quad * 4 + r) * 72 + ct * 16 + m] = f2bf(x);
            }
        }
        __syncthreads();
        {
            u16* yt = Y + (size_t)t * 4096;
            #pragma unroll
            for (int p = 0; p < 2; p++) {
                int id = tid + p * 256;
                u32x4 v = *(const u32x4*)(sOut + (id >> 3) * 72 + (id & 7) * 8);
                *(u32x4*)(yt + id * 8) = v;
            }
        }
        __syncthreads();
    }
    #pragma unroll
    for (int ct = 0; ct < 4; ct++) {
        float s = ssum[ct], q = ssq[ct];
        s += __shfl_xor(s, 16); s += __shfl_xor(s, 32);
        q += __shfl_xor(q, 16); q += __shfl_xor(q, 32);
        if (lane < 16) { atomicAdd(&sSum[ct * 16 + lane], s); atomicAdd(&sSq[ct * 16 + lane], q); }
    }
    __syncthreads();
    if (tid < 64) { atomicAdd(&stats[tid], sSum[tid]); atomicAdd(&stats[64 + tid], sSq[tid]); }
}

// ---- fold BN(prev) into next layer's weights: Wt[n][k] = a[k]*W[k][n] (bf16), b'[n] = b[n] + sum_k c[k]*W[k][n]
__global__ void fin_fold_kernel(const float* __restrict__ stats, float invE,
                                const float* __restrict__ g, const float* __restrict__ be,
                                const float* __restrict__ W, const float* __restrict__ b,
                                u16* __restrict__ wt_out, float* __restrict__ b_out)
{
    int n = threadIdx.x;  // 64 threads
    float bacc = b[n];
    for (int k = 0; k < 64; k++) {
        float mean = stats[k] * invE;
        float var  = stats[64 + k] * invE - mean * mean;
        float a = g[k] / sqrtf(var + BN_EPS);
        float c = be[k] - mean * a;
        float w = W[k * 64 + n];
        wt_out[n * 64 + k] = f2bf(a * w);
        bacc = fmaf(c, w, bacc);
    }
    b_out[n] = bacc;
}

__global__ void fin_affine_kernel(const float* __restrict__ stats, float invE,
                                  const float* __restrict__ g, const float* __restrict__ be,
                                  float* __restrict__ a_out, float* __restrict__ c_out)
{
    int n = threadIdx.x;
    float mean = stats[n] * invE;
    float var  = stats[64 + n] * invE - mean * mean;
    float a = g[n] / sqrtf(var + BN_EPS);
    a_out[n] = a;
    c_out[n] = be[n] - mean * a;
}

// ---- K2/K3: [E,64]@[64,64], weights in registers, A direct from global (bf16)
template<int WF32>
__global__ __launch_bounds__(256) void gemm64_kernel(
    const u16* __restrict__ X, const u16* __restrict__ Wt,
    const float* __restrict__ bias_in, u16* __restrict__ Ybf,
    float* __restrict__ Yf, float* __restrict__ stats, int tiles)
{
    __shared__ u16 sOut[64 * 72];
    __shared__ float sSum[64], sSq[64];
    const int tid = threadIdx.x;
    if (tid < 64) { sSum[tid] = 0.0f; sSq[tid] = 0.0f; }
    __syncthreads();
    const int wave = tid >> 6, lane = tid & 63;
    const int m = lane & 15, quad = lane >> 4;

    bf16x8 Bf[2][4];
    #pragma unroll
    for (int s = 0; s < 2; s++)
        #pragma unroll
        for (int ct = 0; ct < 4; ct++)
            Bf[s][ct] = __builtin_bit_cast(bf16x8,
                *(const u32x4*)(Wt + (ct * 16 + m) * 64 + s * 32 + quad * 8));

    float bias[4], ssum[4] = {0,0,0,0}, ssq[4] = {0,0,0,0};
    #pragma unroll
    for (int ct = 0; ct < 4; ct++) bias[ct] = bias_in[ct * 16 + m];

    for (int t = blockIdx.x; t < tiles; t += gridDim.x) {
        const u16* xp = X + (size_t)(t * 64 + wave * 16 + m) * 64 + quad * 8;
        f32x4 acc[4] = {{0,0,0,0},{0,0,0,0},{0,0,0,0},{0,0,0,0}};
        #pragma unroll
        for (int s = 0; s < 2; s++) {
            bf16x8 af = __builtin_bit_cast(bf16x8, *(const u32x4*)(xp + s * 32));
            #pragma unroll
            for (int ct = 0; ct < 4; ct++)
                acc[ct] = __builtin_amdgcn_mfma_f32_16x16x32_bf16(af, Bf[s][ct], acc[ct], 0, 0, 0);
        }
        #pragma unroll
        for (int ct = 0; ct < 4; ct++) {
            #pragma unroll
            for (int r = 0; r < 4; r++) {
                float x = fmaxf(acc[ct][r] + bias[ct], 0.0f);
                ssum[ct] += x;
                ssq[ct] = fmaf(x, x, ssq[ct]);
                if (WF32)
                    Yf[(size_t)(t * 64 + wave * 16 + quad * 4 + r) * 64 + ct * 16 + m] = x;
                else
                    sOut[(wave * 16 + quad * 4 + r) * 72 + ct * 16 + m] = f2bf(x);
            }
        }
        if (!WF32) {
            __syncthreads();
            u16* yt = Ybf + (size_t)t * 4096;
            #pragma unroll
            for (int p = 0; p < 2; p++) {
                int id = tid + p * 256;
                u32x4 v = *(const u32x4*)(sOut + (id >> 3) * 72 + (id & 7) * 8);
                *(u32x4*)(yt + id * 8) = v;
            }
            __syncthreads();
        }
    }
    #pragma unroll
    for (int ct = 0; ct < 4; ct++) {
        float s = ssum[ct], q = ssq[ct];
        s += __shfl_xor(s, 16); s += __shfl_xor(s, 32);
        q += __shfl_xor(q, 16); q += __shfl_xor(q, 32);
        if (lane < 16) { atomicAdd(&sSum[ct * 16 + lane], s); atomicAdd(&sSq[ct * 16 + lane], q); }
    }
    __syncthreads();
    if (tid < 64) { atomicAdd(&stats[tid], sSum[tid]); atomicAdd(&stats[64 + tid], sSq[tid]); }
}

// ---- K4: final BN3 apply
__global__ __launch_bounds__(256) void bn_apply_bf_kernel(const u16* __restrict__ X,
    const float* __restrict__ a3, const float* __restrict__ c3,
    float* __restrict__ out, int nchunk)
{
    int t0 = blockIdx.x * 256 + threadIdx.x;
    int colb = (t0 & 7) * 8;          // stride % 8 == 0 -> column block fixed per thread
    float a[8], c[8];
    #pragma unroll
    for (int i = 0; i < 8; i++) { a[i] = a3[colb + i]; c[i] = c3[colb + i]; }
    int stride = gridDim.x * 256;
    for (int t = t0; t < nchunk; t += stride) {
        u32x4 v = *(const u32x4*)(X + (size_t)t * 8);
        float4 o0, o1;
        o0.x = fmaf(a[0], bf2f((u16)(v.x & 0xffffu)), c[0]);
        o0.y = fmaf(a[1], bf2f((u16)(v.x >> 16)),     c[1]);
        o0.z = fmaf(a[2], bf2f((u16)(v.y & 0xffffu)), c[2]);
        o0.w = fmaf(a[3], bf2f((u16)(v.y >> 16)),     c[3]);
        o1.x = fmaf(a[4], bf2f((u16)(v.z & 0xffffu)), c[4]);
        o1.y = fmaf(a[5], bf2f((u16)(v.z >> 16)),     c[5]);
        o1.z = fmaf(a[6], bf2f((u16)(v.w & 0xffffu)), c[6]);
        o1.w = fmaf(a[7], bf2f((u16)(v.w >> 16)),     c[7]);
        *(float4*)(out + (size_t)t * 8)     = o0;
        *(float4*)(out + (size_t)t * 8 + 4) = o1;
    }
}

__global__ __launch_bounds__(256) void bn_apply_f32_kernel(float* __restrict__ Y,
    const float* __restrict__ a3, const float* __restrict__ c3, int nchunk)
{
    int t0 = blockIdx.x * 256 + threadIdx.x;
    int colb = (t0 & 7) * 8;
    float a[8], c[8];
    #pragma unroll
    for (int i = 0; i < 8; i++) { a[i] = a3[colb + i]; c[i] = c3[colb + i]; }
    int stride = gridDim.x * 256;
    for (int t = t0; t < nchunk; t += stride) {
        float4 x0 = *(const float4*)(Y + (size_t)t * 8);
        float4 x1 = *(const float4*)(Y + (size_t)t * 8 + 4);
        x0.x = fmaf(a[0], x0.x, c[0]); x0.y = fmaf(a[1], x0.y, c[1]);
        x0.z = fmaf(a[2], x0.z, c[2]); x0.w = fmaf(a[3], x0.w, c[3]);
        x1.x = fmaf(a[4], x1.x, c[4]); x1.y = fmaf(a[5], x1.y, c[5]);
        x1.z = fmaf(a[6], x1.z, c[6]); x1.w = fmaf(a[7], x1.w, c[7]);
        *(float4*)(Y + (size_t)t * 8)     = x0;
        *(float4*)(Y + (size_t)t * 8 + 4) = x1;
    }
}

extern "C" void kernel_launch(void* const* d_in, const int* in_sizes, int n_in,
                              void* d_out, int out_size, void* d_ws, size_t ws_size,
                              hipStream_t stream)
{
    const float* src  = (const float*)d_in[0];
    const float* dst  = (const float*)d_in[1];
    const float* edg  = (const float*)d_in[2];
    const float* gat  = (const float*)d_in[3];
    const int*   batch= (const int*)d_in[4];
    const float* W1 = (const float*)d_in[5];
    const float* b1 = (const float*)d_in[6];
    const float* W2 = (const float*)d_in[7];
    const float* b2 = (const float*)d_in[8];
    const float* W3 = (const float*)d_in[9];
    const float* b3 = (const float*)d_in[10];
    const float* g1 = (const float*)d_in[11];
    const float* be1= (const float*)d_in[12];
    const float* g2 = (const float*)d_in[13];
    const float* be2= (const float*)d_in[14];
    const float* g3 = (const float*)d_in[15];
    const float* be3= (const float*)d_in[16];

    const int E = in_sizes[0] / 64;
    const int tiles = E / 64;                 // E = 1e6 -> 15625 exact
    const float invE = 1.0f / (float)E;

    char* ws = (char*)d_ws;
    u16*   w1f = (u16*)(ws + 0);              // 32768 B fragment-order W1
    u16*   w2t = (u16*)(ws + 36864);          // 8192 B
    u16*   w3t = (u16*)(ws + 45056);          // 8192 B
    float* b2p = (float*)(ws + 53248);
    float* b3p = (float*)(ws + 53504);
    float* st1 = (float*)(ws + 53760);        // st1/st2/st3 contiguous: 384 floats
    float* st2 = (float*)(ws + 54272);
    float* st3 = (float*)(ws + 54784);
    float* a3  = (float*)(ws + 55296);
    float* c3  = (float*)(ws + 55552);

    const size_t OFF_H = 65536;
    const size_t HSZ = (size_t)E * 128;       // one bf16 [E][64] layer

    u16* h1 = (u16*)(ws + OFF_H);
    u16* h2; u16* h3 = nullptr; bool f32out;
    if (ws_size >= OFF_H + 3 * HSZ) {         // tier 1: all three in ws
        h2 = (u16*)(ws + OFF_H + HSZ); h3 = (u16*)(ws + OFF_H + 2 * HSZ); f32out = false;
    } else if (ws_size >= OFF_H + 2 * HSZ) {  // tier 2: h3 -> d_out fp32, in-place BN3
        h2 = (u16*)(ws + OFF_H + HSZ); f32out = true;
    } else {                                  // tier 3: h2 in d_out (scratch), h3 reuses h1 slot
        h2 = (u16*)d_out; h3 = h1; f32out = false;
    }

    prep_kernel<<<64, 256, 0, stream>>>(W1, w1f, st1);
    gemm1_kernel<<<1536, 256, 0, stream>>>(src, dst, edg, gat, batch, w1f, b1, h1, st1, tiles);
    fin_fold_kernel<<<1, 64, 0, stream>>>(st1, invE, g1, be1, W2, b2, w2t, b2p);
    gemm64_kernel<0><<<1536, 256, 0, stream>>>(h1, w2t, b2p, h2, nullptr, st2, tiles);
    fin_fold_kernel<<<1, 64, 0, stream>>>(st2, invE, g2, be2, W3, b3, w3t, b3p);
    if (!f32out) {
        gemm64_kernel<0><<<1536, 256, 0, stream>>>(h2, w3t, b3p, h3, nullptr, st3, tiles);
        fin_affine_kernel<<<1, 64, 0, stream>>>(st3, invE, g3, be3, a3, c3);
        bn_apply_bf_kernel<<<4096, 256, 0, stream>>>(h3, a3, c3, (float*)d_out, E * 8);
    } else {
        gemm64_kernel<1><<<1536, 256, 0, stream>>>(h2, w3t, b3p, nullptr, (float*)d_out, st3, tiles);
        fin_affine_kernel<<<1, 64, 0, stream>>>(st3, invE, g3, be3, a3, c3);
        bn_apply_f32_kernel<<<4096, 256, 0, stream>>>((float*)d_out, a3, c3, E * 8);
    }
}

// Round 2
// 938.611 us; speedup vs baseline: 1.0695x; 1.0695x over previous
//
#include <hip/hip_runtime.h>

// MEGNet edge conv, latency-optimized:
//  prep : W1 -> MFMA-fragment-order bf16 + zero stats
//  K1   : gather-concat GEMM [E,256]@[256,64], all loads hoisted, batch prefetch,
//         per-wave LDS epilogue (no block barriers), h1 bf16, stats1 atomics
//  K2   : fold BN1 into W2 in-kernel; [E,64]@[64,64], 4 subtiles of loads in
//         flight per wave, h2 bf16, stats2
//  K3   : fold BN2 into W3; stats-only pass over h2 (no stores) -> stats3
//  K4   : fold BN2 into W3 + BN3 affine; recompute GEMM3 from h2, apply affine,
//         store fp32 out (h3 never materialized)

typedef unsigned short u16;
typedef unsigned int u32;
using bf16x8 = __bf16 __attribute__((ext_vector_type(8)));
using f32x4  = float __attribute__((ext_vector_type(4)));
using u32x4  = u32 __attribute__((ext_vector_type(4)));

#define BN_EPS 1e-5f

__device__ __forceinline__ u16 f2bf(float f) {
    u32 u = __builtin_bit_cast(u32, f);
    u += 0x7fffu + ((u >> 16) & 1u);   // RNE (finite inputs)
    return (u16)(u >> 16);
}
__device__ __forceinline__ u32 pk2(float a, float b) {
    return (u32)f2bf(a) | ((u32)f2bf(b) << 16);
}

// ---- prep: W1 -> fragment-order bf16; zero the 384 stats floats
__global__ __launch_bounds__(256) void prep_kernel(const float* __restrict__ W1,
                                                   u16* __restrict__ w1f,
                                                   float* __restrict__ statsz) {
    int t = blockIdx.x * 256 + threadIdx.x;
    if (t < 16384) {
        int j = t & 7, lane = (t >> 3) & 63, ct = (t >> 9) & 3, s = (t >> 11) & 1, c = t >> 12;
        int m = lane & 15, quad = lane >> 4;
        int k = c * 64 + s * 32 + quad * 8 + j;
        int n = ct * 16 + m;
        w1f[t] = f2bf(W1[k * 64 + n]);
    }
    if (t < 384) statsz[t] = 0.0f;
}

// ---- K1: concat GEMM, K=256; loads fully hoisted; per-wave epilogue
__global__ __launch_bounds__(256) void gemm1_kernel(
    const float* __restrict__ src, const float* __restrict__ dst,
    const float* __restrict__ edg, const float* __restrict__ gat,
    const int* __restrict__ batch, const u16* __restrict__ w1f,
    const float* __restrict__ b1, u16* __restrict__ Y,
    float* __restrict__ stats, int tiles)
{
    __shared__ u16 sW[16384];         // fragment-order W1 (32 KB)
    __shared__ u16 sOut[4][1152];     // per-wave 16x72 staging
    __shared__ float sSum[64], sSq[64];
    const int tid = threadIdx.x;
    {
        const u32x4* g = (const u32x4*)w1f;
        u32x4* l = (u32x4*)sW;
        #pragma unroll
        for (int i = 0; i < 8; i++) l[tid + i * 256] = g[tid + i * 256];
    }
    if (tid < 64) { sSum[tid] = 0.f; sSq[tid] = 0.f; }
    __syncthreads();

    const int wave = tid >> 6, lane = tid & 63;
    const int m = lane & 15, quad = lane >> 4;
    const u32x4* sWv = (const u32x4*)sW;
    u16* so = sOut[wave];

    float bias[4];
    #pragma unroll
    for (int ct = 0; ct < 4; ct++) bias[ct] = b1[ct * 16 + m];
    float ssum[4] = {0,0,0,0}, ssq[4] = {0,0,0,0};

    const int gs = gridDim.x;
    const int rowoff = wave * 16 + m;
    int t = blockIdx.x;
    int bi = (t < tiles) ? batch[(size_t)t * 64 + rowoff] : 0;

    for (; t < tiles; t += gs) {
        const size_t rbase = (size_t)t * 64 + wave * 16;
        float4 L[16];
        {
            const float* p0 = src + (rbase + m) * 64 + quad * 8;
            const float* p1 = dst + (rbase + m) * 64 + quad * 8;
            const float* p2 = edg + (rbase + m) * 64 + quad * 8;
            const float* p3 = gat + (size_t)bi * 64 + quad * 8;
            L[0]  = *(const float4*)(p0);      L[1]  = *(const float4*)(p0 + 4);
            L[2]  = *(const float4*)(p0 + 32); L[3]  = *(const float4*)(p0 + 36);
            L[4]  = *(const float4*)(p1);      L[5]  = *(const float4*)(p1 + 4);
            L[6]  = *(const float4*)(p1 + 32); L[7]  = *(const float4*)(p1 + 36);
            L[8]  = *(const float4*)(p2);      L[9]  = *(const float4*)(p2 + 4);
            L[10] = *(const float4*)(p2 + 32); L[11] = *(const float4*)(p2 + 36);
            L[12] = *(const float4*)(p3);      L[13] = *(const float4*)(p3 + 4);
            L[14] = *(const float4*)(p3 + 32); L[15] = *(const float4*)(p3 + 36);
        }
        int tn = t + gs;
        int bn = (tn < tiles) ? batch[(size_t)tn * 64 + rowoff] : 0;

        f32x4 acc[4] = {{0,0,0,0},{0,0,0,0},{0,0,0,0},{0,0,0,0}};
        #pragma unroll
        for (int c = 0; c < 4; c++) {
            #pragma unroll
            for (int s = 0; s < 2; s++) {
                float4 f0 = L[c * 4 + s * 2], f1 = L[c * 4 + s * 2 + 1];
                u32x4 av = { pk2(f0.x, f0.y), pk2(f0.z, f0.w),
                             pk2(f1.x, f1.y), pk2(f1.z, f1.w) };
                bf16x8 af = __builtin_bit_cast(bf16x8, av);
                #pragma unroll
                for (int ct = 0; ct < 4; ct++) {
                    bf16x8 bf = __builtin_bit_cast(bf16x8, sWv[((c * 2 + s) * 4 + ct) * 64 + lane]);
                    acc[ct] = __builtin_amdgcn_mfma_f32_16x16x32_bf16(af, bf, acc[ct], 0, 0, 0);
                }
            }
        }
        #pragma unroll
        for (int ct = 0; ct < 4; ct++) {
            #pragma unroll
            for (int r = 0; r < 4; r++) {
                float x = fmaxf(acc[ct][r] + bias[ct], 0.f);
                ssum[ct] += x; ssq[ct] = fmaf(x, x, ssq[ct]);
                so[(quad * 4 + r) * 72 + ct * 16 + m] = f2bf(x);
            }
        }
        __threadfence_block();     // wave-internal LDS ordering; no block barrier
        {
            int row = lane >> 2, seg = lane & 3;
            const u16* rp = so + row * 72 + seg * 16;
            u32x4 v0 = *(const u32x4*)rp;
            u32x4 v1 = *(const u32x4*)(rp + 8);
            u16* yp = Y + (rbase + row) * 64 + seg * 16;
            *(u32x4*)yp = v0;
            *(u32x4*)(yp + 8) = v1;
        }
        bi = bn;
    }
    #pragma unroll
    for (int ct = 0; ct < 4; ct++) {
        float s = ssum[ct], q = ssq[ct];
        s += __shfl_xor(s, 16); s += __shfl_xor(s, 32);
        q += __shfl_xor(q, 16); q += __shfl_xor(q, 32);
        if (lane < 16) { atomicAdd(&sSum[ct * 16 + lane], s); atomicAdd(&sSq[ct * 16 + lane], q); }
    }
    __syncthreads();
    if (tid < 64) { atomicAdd(&stats[tid], sSum[tid]); atomicAdd(&stats[64 + tid], sSq[tid]); }
}

// ---- shared preamble: fold BN(stats_in,g,be) into W,b -> per-lane fragments
// Produces Bf[s][ct] (B-fragment, bf16) and bias[ct] in registers.
#define FOLD_PREAMBLE(STATS, G, BE, W, B)                                      \
    for (int i = tid; i < 1024; i += 256)                                      \
        ((float4*)sWf)[i] = ((const float4*)(W))[i];                           \
    if (tid < 64) {                                                            \
        float mean = (STATS)[tid] * invE;                                      \
        float var  = (STATS)[64 + tid] * invE - mean * mean;                   \
        float a = (G)[tid] / sqrtf(var + BN_EPS);                              \
        sAc[tid] = a; sCc[tid] = (BE)[tid] - mean * a;                         \
        sSum[tid] = 0.f; sSq[tid] = 0.f;                                       \
    }                                                                          \
    __syncthreads();                                                           \
    if (tid < 64) {                                                            \
        float bacc = (B)[tid];                                                 \
        for (int k = 0; k < 64; k++) bacc = fmaf(sCc[k], sWf[k * 64 + tid], bacc); \
        sBp[tid] = bacc;                                                       \
    }                                                                          \
    __syncthreads();                                                           \
    bf16x8 Bf[2][4];                                                           \
    float bias[4];                                                             \
    {                                                                          \
        _Pragma("unroll")                                                      \
        for (int s = 0; s < 2; s++) {                                          \
            _Pragma("unroll")                                                  \
            for (int ct = 0; ct < 4; ct++) {                                   \
                int n = ct * 16 + m;                                           \
                u32x4 wv;                                                      \
                _Pragma("unroll")                                              \
                for (int jj = 0; jj < 4; jj++) {                               \
                    int k = s * 32 + quad * 8 + jj * 2;                        \
                    wv[jj] = pk2(sAc[k] * sWf[k * 64 + n],                     \
                                 sAc[k + 1] * sWf[(k + 1) * 64 + n]);          \
                }                                                              \
                Bf[s][ct] = __builtin_bit_cast(bf16x8, wv);                    \
            }                                                                  \
        }                                                                      \
        _Pragma("unroll")                                                      \
        for (int ct = 0; ct < 4; ct++) bias[ct] = sBp[ct * 16 + m];            \
    }

// ---- K2: fold(BN1)->W2; GEMM; store h2 bf16; stats2
__global__ __launch_bounds__(256) void gemm_mid_kernel(
    const u16* __restrict__ X, const float* __restrict__ W, const float* __restrict__ b,
    const float* __restrict__ stats_in, float invE,
    const float* __restrict__ g, const float* __restrict__ be,
    u16* __restrict__ Y, float* __restrict__ stats_out, int tiles)
{
    __shared__ float sWf[4096];
    __shared__ float sAc[64], sCc[64], sBp[64];
    __shared__ float sSum[64], sSq[64];
    __shared__ u16 sOut[4][1152];
    const int tid = threadIdx.x;
    const int wave = tid >> 6, lane = tid & 63;
    const int m = lane & 15, quad = lane >> 4;

    FOLD_PREAMBLE(stats_in, g, be, W, b)

    float ssum[4] = {0,0,0,0}, ssq[4] = {0,0,0,0};
    u16* so = sOut[wave];
    const int nw = gridDim.x * 4;
    for (int t = blockIdx.x * 4 + wave; t < tiles; t += nw) {
        u32x4 Xf[8];
        const u16* xb = X + (size_t)t * 4096 + m * 64 + quad * 8;
        #pragma unroll
        for (int u = 0; u < 4; u++) {
            Xf[u * 2]     = *(const u32x4*)(xb + u * 1024);
            Xf[u * 2 + 1] = *(const u32x4*)(xb + u * 1024 + 32);
        }
        #pragma unroll
        for (int u = 0; u < 4; u++) {
            f32x4 acc[4] = {{0,0,0,0},{0,0,0,0},{0,0,0,0},{0,0,0,0}};
            #pragma unroll
            for (int s = 0; s < 2; s++) {
                bf16x8 af = __builtin_bit_cast(bf16x8, Xf[u * 2 + s]);
                #pragma unroll
                for (int ct = 0; ct < 4; ct++)
                    acc[ct] = __builtin_amdgcn_mfma_f32_16x16x32_bf16(af, Bf[s][ct], acc[ct], 0, 0, 0);
            }
            #pragma unroll
            for (int ct = 0; ct < 4; ct++) {
                #pragma unroll
                for (int r = 0; r < 4; r++) {
                    float x = fmaxf(acc[ct][r] + bias[ct], 0.f);
                    ssum[ct] += x; ssq[ct] = fmaf(x, x, ssq[ct]);
                    so[(quad * 4 + r) * 72 + ct * 16 + m] = f2bf(x);
                }
            }
            __threadfence_block();
            int row = lane >> 2, seg = lane & 3;
            const u16* rp = so + row * 72 + seg * 16;
            u32x4 v0 = *(const u32x4*)rp;
            u32x4 v1 = *(const u32x4*)(rp + 8);
            u16* yp = Y + (size_t)t * 4096 + (u * 16 + row) * 64 + seg * 16;
            *(u32x4*)yp = v0;
            *(u32x4*)(yp + 8) = v1;
        }
    }
    #pragma unroll
    for (int ct = 0; ct < 4; ct++) {
        float s = ssum[ct], q = ssq[ct];
        s += __shfl_xor(s, 16); s += __shfl_xor(s, 32);
        q += __shfl_xor(q, 16); q += __shfl_xor(q, 32);
        if (lane < 16) { atomicAdd(&sSum[ct * 16 + lane], s); atomicAdd(&sSq[ct * 16 + lane], q); }
    }
    __syncthreads();
    if (tid < 64) { atomicAdd(&stats_out[tid], sSum[tid]); atomicAdd(&stats_out[64 + tid], sSq[tid]); }
}

// ---- K3: fold(BN2)->W3; stats-only pass over h2 (no stores)
__global__ __launch_bounds__(256) void gemm_stats_kernel(
    const u16* __restrict__ X, const float* __restrict__ W, const float* __restrict__ b,
    const float* __restrict__ stats_in, float invE,
    const float* __restrict__ g, const float* __restrict__ be,
    float* __restrict__ stats_out, int tiles)
{
    __shared__ float sWf[4096];
    __shared__ float sAc[64], sCc[64], sBp[64];
    __shared__ float sSum[64], sSq[64];
    const int tid = threadIdx.x;
    const int wave = tid >> 6, lane = tid & 63;
    const int m = lane & 15, quad = lane >> 4;

    FOLD_PREAMBLE(stats_in, g, be, W, b)

    float ssum[4] = {0,0,0,0}, ssq[4] = {0,0,0,0};
    const int nw = gridDim.x * 4;
    for (int t = blockIdx.x * 4 + wave; t < tiles; t += nw) {
        u32x4 Xf[8];
        const u16* xb = X + (size_t)t * 4096 + m * 64 + quad * 8;
        #pragma unroll
        for (int u = 0; u < 4; u++) {
            Xf[u * 2]     = *(const u32x4*)(xb + u * 1024);
            Xf[u * 2 + 1] = *(const u32x4*)(xb + u * 1024 + 32);
        }
        #pragma unroll
        for (int u = 0; u < 4; u++) {
            f32x4 acc[4] = {{0,0,0,0},{0,0,0,0},{0,0,0,0},{0,0,0,0}};
            #pragma unroll
            for (int s = 0; s < 2; s++) {
                bf16x8 af = __builtin_bit_cast(bf16x8, Xf[u * 2 + s]);
                #pragma unroll
                for (int ct = 0; ct < 4; ct++)
                    acc[ct] = __builtin_amdgcn_mfma_f32_16x16x32_bf16(af, Bf[s][ct], acc[ct], 0, 0, 0);
            }
            #pragma unroll
            for (int ct = 0; ct < 4; ct++) {
                #pragma unroll
                for (int r = 0; r < 4; r++) {
                    float x = fmaxf(acc[ct][r] + bias[ct], 0.f);
                    ssum[ct] += x; ssq[ct] = fmaf(x, x, ssq[ct]);
                }
            }
        }
    }
    #pragma unroll
    for (int ct = 0; ct < 4; ct++) {
        float s = ssum[ct], q = ssq[ct];
        s += __shfl_xor(s, 16); s += __shfl_xor(s, 32);
        q += __shfl_xor(q, 16); q += __shfl_xor(q, 32);
        if (lane < 16) { atomicAdd(&sSum[ct * 16 + lane], s); atomicAdd(&sSq[ct * 16 + lane], q); }
    }
    __syncthreads();
    if (tid < 64) { atomicAdd(&stats_out[tid], sSum[tid]); atomicAdd(&stats_out[64 + tid], sSq[tid]); }
}

// ---- K4: fold(BN2)->W3 + BN3 affine; recompute GEMM3; store fp32 out
__global__ __launch_bounds__(256) void gemm_out_kernel(
    const u16* __restrict__ X, const float* __restrict__ W, const float* __restrict__ b,
    const float* __restrict__ stats_in, float invE,
    const float* __restrict__ g, const float* __restrict__ be,
    const float* __restrict__ stats3, const float* __restrict__ g3,
    const float* __restrict__ be3, float* __restrict__ out, int tiles)
{
    __shared__ float sWf[4096];
    __shared__ float sAc[64], sCc[64], sBp[64];
    __shared__ float sSum[64], sSq[64];
    __shared__ float sA3[64], sC3[64];
    __shared__ float sOutF[4][1088];   // per-wave 16x68 fp32
    const int tid = threadIdx.x;
    const int wave = tid >> 6, lane = tid & 63;
    const int m = lane & 15, quad = lane >> 4;

    if (tid < 64) {
        float mean = stats3[tid] * invE;
        float var  = stats3[64 + tid] * invE - mean * mean;
        float a = g3[tid] / sqrtf(var + BN_EPS);
        sA3[tid] = a; sC3[tid] = be3[tid] - mean * a;
    }
    FOLD_PREAMBLE(stats_in, g, be, W, b)

    float a3r[4], c3r[4];
    #pragma unroll
    for (int ct = 0; ct < 4; ct++) { a3r[ct] = sA3[ct * 16 + m]; c3r[ct] = sC3[ct * 16 + m]; }

    float* sof = sOutF[wave];
    const int nw = gridDim.x * 4;
    for (int t = blockIdx.x * 4 + wave; t < tiles; t += nw) {
        u32x4 Xf[8];
        const u16* xb = X + (size_t)t * 4096 + m * 64 + quad * 8;
        #pragma unroll
        for (int u = 0; u < 4; u++) {
            Xf[u * 2]     = *(const u32x4*)(xb + u * 1024);
            Xf[u * 2 + 1] = *(const u32x4*)(xb + u * 1024 + 32);
        }
        #pragma unroll
        for (int u = 0; u < 4; u++) {
            f32x4 acc[4] = {{0,0,0,0},{0,0,0,0},{0,0,0,0},{0,0,0,0}};
            #pragma unroll
            for (int s = 0; s < 2; s++) {
                bf16x8 af = __builtin_bit_cast(bf16x8, Xf[u * 2 + s]);
                #pragma unroll
                for (int ct = 0; ct < 4; ct++)
                    acc[ct] = __builtin_amdgcn_mfma_f32_16x16x32_bf16(af, Bf[s][ct], acc[ct], 0, 0, 0);
            }
            #pragma unroll
            for (int ct = 0; ct < 4; ct++) {
                #pragma unroll
                for (int r = 0; r < 4; r++) {
                    float x = fmaxf(acc[ct][r] + bias[ct], 0.f);
                    sof[(quad * 4 + r) * 68 + ct * 16 + m] = fmaf(a3r[ct], x, c3r[ct]);
                }
            }
            __threadfence_block();
            int row = lane >> 2, seg = lane & 3;
            const float* rp = sof + row * 68 + seg * 16;
            float4 v0 = *(const float4*)rp;
            float4 v1 = *(const float4*)(rp + 4);
            float4 v2 = *(const float4*)(rp + 8);
            float4 v3 = *(const float4*)(rp + 12);
            float* op = out + ((size_t)t * 64 + u * 16 + row) * 64 + seg * 16;
            *(float4*)op       = v0;
            *(float4*)(op + 4) = v1;
            *(float4*)(op + 8) = v2;
            *(float4*)(op + 12) = v3;
        }
    }
    (void)sSum; (void)sSq;
}

extern "C" void kernel_launch(void* const* d_in, const int* in_sizes, int n_in,
                              void* d_out, int out_size, void* d_ws, size_t ws_size,
                              hipStream_t stream)
{
    const float* src  = (const float*)d_in[0];
    const float* dst  = (const float*)d_in[1];
    const float* edg  = (const float*)d_in[2];
    const float* gat  = (const float*)d_in[3];
    const int*   batch= (const int*)d_in[4];
    const float* W1 = (const float*)d_in[5];
    const float* b1 = (const float*)d_in[6];
    const float* W2 = (const float*)d_in[7];
    const float* b2 = (const float*)d_in[8];
    const float* W3 = (const float*)d_in[9];
    const float* b3 = (const float*)d_in[10];
    const float* g1 = (const float*)d_in[11];
    const float* be1= (const float*)d_in[12];
    const float* g2 = (const float*)d_in[13];
    const float* be2= (const float*)d_in[14];
    const float* g3 = (const float*)d_in[15];
    const float* be3= (const float*)d_in[16];

    const int E = in_sizes[0] / 64;
    const int tiles = E / 64;
    const float invE = 1.0f / (float)E;

    char* ws = (char*)d_ws;
    u16*   w1f = (u16*)(ws + 0);            // 32 KB
    float* st1 = (float*)(ws + 49152);      // 3x128 floats contiguous
    float* st2 = st1 + 128;
    float* st3 = st1 + 256;

    const size_t OFF_H = 65536;
    const size_t HSZ = (size_t)E * 128;     // bf16 [E][64]
    u16 *h1, *h2;
    if (ws_size >= OFF_H + 2 * HSZ) {
        h1 = (u16*)(ws + OFF_H); h2 = (u16*)(ws + OFF_H + HSZ);
    } else {  // h1 borrows d_out (dead before K4 writes out); h2 in ws
        h1 = (u16*)d_out; h2 = (u16*)(ws + OFF_H);
    }

    prep_kernel<<<64, 256, 0, stream>>>(W1, w1f, st1);
    gemm1_kernel<<<1536, 256, 0, stream>>>(src, dst, edg, gat, batch, w1f, b1, h1, st1, tiles);
    gemm_mid_kernel<<<1024, 256, 0, stream>>>(h1, W2, b2, st1, invE, g1, be1, h2, st2, tiles);
    gemm_stats_kernel<<<1024, 256, 0, stream>>>(h2, W3, b3, st2, invE, g2, be2, st3, tiles);
    gemm_out_kernel<<<1024, 256, 0, stream>>>(h2, W3, b3, st2, invE, g2, be2, st3, g3, be3,
                                              (float*)d_out, tiles);
}